// Round 3
// baseline (144.056 us; speedup 1.0000x reference)
//
#include <hip/hip_runtime.h>
#include <hip/hip_bf16.h>

// GCNConvAdj: out = D^-1/2 (A+I) D^-1/2 (x W) + b
// B=8, N=2048, F_IN=F_OUT=256. f32 in/out; bf16 MFMA internals.
// R3: no adjBF materialization. gemm2 reads adj f32 (L3-resident after deg),
// converts in-register while staging A; B (gT) via global_load_lds.
#define BB 8
#define NN 2048
#define FF 256
#define NT (NN / 64)   // 32 K-steps of BK=64

typedef __attribute__((ext_vector_type(8))) short short8;
typedef __attribute__((ext_vector_type(4))) short short4v;
typedef __attribute__((ext_vector_type(4))) float f32x4;
typedef __hip_bfloat16 bf16;

__device__ inline short f2bf(float x) {
  unsigned u = __builtin_bit_cast(unsigned, x);
  unsigned r = (u + 0x7fffu + ((u >> 16) & 1u)) >> 16;
  return (short)r;
}

__device__ inline void gl2lds16(const void* g, void* l) {
  __builtin_amdgcn_global_load_lds((const __attribute__((address_space(1))) void*)g,
                                   (__attribute__((address_space(3))) void*)l, 16, 0, 0);
}

// ------- kernel 1: deg (dis = rsqrt(rowsum(adj)+1)) + wt (WT[o][k]=bf16 W) --
__global__ __launch_bounds__(256)
void deg_wt_kernel(const float* __restrict__ adj, const float* __restrict__ W,
                   float* __restrict__ dis, bf16* __restrict__ WT) {
  if (blockIdx.x >= BB * NN / 4) {
    // wt part: 64 blocks, 4 elements/thread
    int t2 = (blockIdx.x - BB * NN / 4) * 256 + threadIdx.x;   // 0..16383
    int k = t2 >> 6, oc = (t2 & 63) * 4;
    float4 v = *reinterpret_cast<const float4*>(W + (size_t)k * FF + oc);
    *reinterpret_cast<short*>(WT + (size_t)(oc + 0) * FF + k) = f2bf(v.x);
    *reinterpret_cast<short*>(WT + (size_t)(oc + 1) * FF + k) = f2bf(v.y);
    *reinterpret_cast<short*>(WT + (size_t)(oc + 2) * FF + k) = f2bf(v.z);
    *reinterpret_cast<short*>(WT + (size_t)(oc + 3) * FF + k) = f2bf(v.w);
    return;
  }
  int wid = threadIdx.x >> 6, lane = threadIdx.x & 63;
  int row = blockIdx.x * 4 + wid;                       // 0 .. BB*NN-1
  const float4* a4 = reinterpret_cast<const float4*>(adj + (size_t)row * NN);
  float s = 0.f;
#pragma unroll
  for (int i = 0; i < 8; i++) {
    float4 v = a4[lane + 64 * i];
    s += v.x + v.y + v.z + v.w;
  }
#pragma unroll
  for (int off = 1; off < 64; off <<= 1) s += __shfl_xor(s, off, 64);
  if (lane == 0) dis[row] = rsqrtf(s + 1.0f);
}

// ---------------- kernel 2: gT[b][o][m] = dis[m] * (x@W)[m][o] (bf16) -------
__global__ __launch_bounds__(256)
void gemm1_kernel(const float* __restrict__ x, const bf16* __restrict__ WT,
                  const float* __restrict__ dis, bf16* __restrict__ gT) {
  __shared__ bf16 lA[128][40];
  __shared__ bf16 lB[128][40];
  int bid = blockIdx.x;
  int mtile = bid & 127, otile = bid >> 7;   // pair o-tiles on same XCD
  int m0 = mtile * 128, o0 = otile * 128;
  int t = threadIdx.x, wid = t >> 6, lane = t & 63;
  int wr = wid >> 1, wc = wid & 1;
  int srow = t >> 1, sseg = t & 1;
  const int r16 = lane & 15, kb = lane >> 4;

  f32x4 acc[4][4];
#pragma unroll
  for (int i = 0; i < 4; i++)
#pragma unroll
    for (int j = 0; j < 4; j++) acc[i][j] = (f32x4){0.f, 0.f, 0.f, 0.f};

  for (int k0 = 0; k0 < FF; k0 += 32) {
    {
      const float4* ap = reinterpret_cast<const float4*>(
          x + (size_t)(m0 + srow) * FF + k0 + sseg * 16);
      float arr[16];
      float4 v0 = ap[0], v1 = ap[1], v2 = ap[2], v3 = ap[3];
      arr[0]=v0.x; arr[1]=v0.y; arr[2]=v0.z; arr[3]=v0.w;
      arr[4]=v1.x; arr[5]=v1.y; arr[6]=v1.z; arr[7]=v1.w;
      arr[8]=v2.x; arr[9]=v2.y; arr[10]=v2.z; arr[11]=v2.w;
      arr[12]=v3.x; arr[13]=v3.y; arr[14]=v3.z; arr[15]=v3.w;
      short8 w0, w1;
#pragma unroll
      for (int e = 0; e < 8; e++) { w0[e] = f2bf(arr[e]); w1[e] = f2bf(arr[8 + e]); }
      *reinterpret_cast<short8*>(&lA[srow][sseg * 16]) = w0;
      *reinterpret_cast<short8*>(&lA[srow][sseg * 16 + 8]) = w1;
    }
    {
      const short8* bp = reinterpret_cast<const short8*>(
          WT + (size_t)(o0 + srow) * FF + k0 + sseg * 16);
      *reinterpret_cast<short8*>(&lB[srow][sseg * 16]) = bp[0];
      *reinterpret_cast<short8*>(&lB[srow][sseg * 16 + 8]) = bp[1];
    }
    __syncthreads();
    short8 af[4], bfr[4];
#pragma unroll
    for (int mf = 0; mf < 4; mf++)
      af[mf] = *reinterpret_cast<const short8*>(&lA[wr * 64 + mf * 16 + r16][kb * 8]);
#pragma unroll
    for (int nf = 0; nf < 4; nf++)
      bfr[nf] = *reinterpret_cast<const short8*>(&lB[wc * 64 + nf * 16 + r16][kb * 8]);
#pragma unroll
    for (int mf = 0; mf < 4; mf++)
#pragma unroll
      for (int nf = 0; nf < 4; nf++)
        acc[mf][nf] = __builtin_amdgcn_mfma_f32_16x16x32_bf16(af[mf], bfr[nf], acc[mf][nf], 0, 0, 0);
    __syncthreads();
  }

  int b = m0 >> 11;
#pragma unroll
  for (int mf = 0; mf < 4; mf++) {
    int mloc = wr * 64 + mf * 16 + (lane >> 4) * 4;
    int mg = m0 + mloc;
    float4 d4 = *reinterpret_cast<const float4*>(dis + mg);
#pragma unroll
    for (int nf = 0; nf < 4; nf++) {
      int o = o0 + wc * 64 + nf * 16 + r16;
      f32x4 v = acc[mf][nf];
      short4v w;
      w[0] = f2bf(v[0] * d4.x); w[1] = f2bf(v[1] * d4.y);
      w[2] = f2bf(v[2] * d4.z); w[3] = f2bf(v[3] * d4.w);
      *reinterpret_cast<short4v*>(gT + ((size_t)b * FF + o) * NN + (mg & (NN - 1))) = w;
    }
  }
}

// ------- kernel 3: out[b][n][o] = dis[n]*((adj+I)@g)[n][o] + bias[o] --------
// BM=128, BN=64, BK=64. 512 blocks (2/CU). A: f32 reg-stage + convert + XOR-
// swizzled ds_write (dbuf). B: global_load_lds w/ pre-swizzled source. The 4
// o-blocks of one (batch,mtile) share an XCD (bid%8 invariant).
__global__ __launch_bounds__(256, 2)
void gemm2_kernel(const float* __restrict__ adj, const bf16* __restrict__ gT,
                  const float* __restrict__ dis, const float* __restrict__ bias,
                  float* __restrict__ out) {
  __shared__ __align__(16) bf16 lA[2][128 * 64];   // 32 KB
  __shared__ __align__(16) bf16 lB[2][64 * 64];    // 16 KB
  int bid = blockIdx.x;
  int g = bid & 127, ob = bid >> 7;
  int batch = g >> 4, mtile = g & 15;
  int n0 = mtile * 128, o0 = ob * 64;
  const float* A = adj + (size_t)batch * NN * NN;
  const bf16* Bt = gT + (size_t)batch * FF * NN;

  int t = threadIdx.x, wid = t >> 6, lane = t & 63;
  int wr = wid >> 1, wc = wid & 1;               // wave tile 64(M) x 32(N)
  const int r16 = lane & 15, kb = lane >> 4;

  // A staging: thread -> row (2 threads/row), col-half of 32 f32
  int arow = t >> 1, ahalf = t & 1;
  const float4* aptr = reinterpret_cast<const float4*>(
      A + (size_t)(n0 + arow) * NN) + ahalf * 8;
  // B staging: 2 gload_lds/thread
  int btr = t >> 3, bts = t & 7;

  f32x4 acc[4][2];
#pragma unroll
  for (int i = 0; i < 4; i++)
#pragma unroll
    for (int j = 0; j < 2; j++) acc[i][j] = (f32x4){0.f, 0.f, 0.f, 0.f};

  float4 ar[8];
  auto loadA = [&](int ks) {
#pragma unroll
    for (int q = 0; q < 8; q++) ar[q] = aptr[ks * 16 + q];
  };
  auto stageB = [&](int buf, int ks) {
#pragma unroll
    for (int q = 0; q < 2; q++) {
      int r = q * 32 + btr;
      gl2lds16(Bt + (size_t)(o0 + r) * NN + ks * 64 + 8 * (bts ^ (r & 7)),
               &lB[buf][r * 64 + bts * 8]);
    }
  };
  auto convA = [&](int buf, int ks) {
    int k0 = ks * 64;
    if (k0 >= n0 && k0 < n0 + 128) {             // diagonal inside this K-tile
      int dcol = (n0 + arow) - (k0 + 32 * ahalf);
#pragma unroll
      for (int q = 0; q < 8; q++) {
        ar[q].x += (dcol == 4 * q + 0) ? 1.0f : 0.0f;
        ar[q].y += (dcol == 4 * q + 1) ? 1.0f : 0.0f;
        ar[q].z += (dcol == 4 * q + 2) ? 1.0f : 0.0f;
        ar[q].w += (dcol == 4 * q + 3) ? 1.0f : 0.0f;
      }
    }
#pragma unroll
    for (int s4 = 0; s4 < 4; s4++) {
      short8 w;
      w[0] = f2bf(ar[2 * s4].x); w[1] = f2bf(ar[2 * s4].y);
      w[2] = f2bf(ar[2 * s4].z); w[3] = f2bf(ar[2 * s4].w);
      w[4] = f2bf(ar[2 * s4 + 1].x); w[5] = f2bf(ar[2 * s4 + 1].y);
      w[6] = f2bf(ar[2 * s4 + 1].z); w[7] = f2bf(ar[2 * s4 + 1].w);
      int slot = (4 * ahalf + s4) ^ (arow & 7);
      *reinterpret_cast<short8*>(&lA[buf][arow * 64 + slot * 8]) = w;
    }
  };

  // prologue
  loadA(0);
  stageB(0, 0);
  convA(0, 0);
  __syncthreads();

  int cur = 0;
#pragma unroll 1
  for (int ks = 0; ks < NT; ++ks) {
    int nxt = cur ^ 1;
    bool more = (ks + 1 < NT);
    if (more) { stageB(nxt, ks + 1); loadA(ks + 1); }
    const bf16* sa = lA[cur];
    const bf16* sb = lB[cur];
#pragma unroll
    for (int kk = 0; kk < 2; kk++) {
      short8 af[4], bfr[2];
#pragma unroll
      for (int mf = 0; mf < 4; mf++) {
        int ra = wr * 64 + mf * 16 + r16;
        int slot = ((kk << 2) | kb) ^ (ra & 7);
        af[mf] = *reinterpret_cast<const short8*>(&sa[ra * 64 + slot * 8]);
      }
#pragma unroll
      for (int nf = 0; nf < 2; nf++) {
        int rb = wc * 32 + nf * 16 + r16;
        int slot = ((kk << 2) | kb) ^ (rb & 7);
        bfr[nf] = *reinterpret_cast<const short8*>(&sb[rb * 64 + slot * 8]);
      }
#pragma unroll
      for (int mf = 0; mf < 4; mf++)
#pragma unroll
        for (int nf = 0; nf < 2; nf++)
          acc[mf][nf] = __builtin_amdgcn_mfma_f32_16x16x32_bf16(af[mf], bfr[nf], acc[mf][nf], 0, 0, 0);
    }
    if (more) convA(nxt, ks + 1);
    __syncthreads();
    cur = nxt;
  }

  // epilogue: out = dis[n]*acc + bias[o]
  const float* disb = dis + (size_t)batch * NN;
  float bv[2];
#pragma unroll
  for (int nf = 0; nf < 2; nf++) bv[nf] = bias[o0 + wc * 32 + nf * 16 + r16];
#pragma unroll
  for (int mf = 0; mf < 4; mf++) {
    int ng = n0 + wr * 64 + mf * 16 + (lane >> 4) * 4;
    float4 d4 = *reinterpret_cast<const float4*>(disb + ng);
    float* op0 = out + ((size_t)batch * NN + ng) * FF;
#pragma unroll
    for (int nf = 0; nf < 2; nf++) {
      int o = o0 + wc * 32 + nf * 16 + r16;
      f32x4 v = acc[mf][nf];
      op0[0 * FF + o] = v[0] * d4.x + bv[nf];
      op0[1 * FF + o] = v[1] * d4.y + bv[nf];
      op0[2 * FF + o] = v[2] * d4.z + bv[nf];
      op0[3 * FF + o] = v[3] * d4.w + bv[nf];
    }
  }
}

extern "C" void kernel_launch(void* const* d_in, const int* in_sizes, int n_in,
                              void* d_out, int out_size, void* d_ws, size_t ws_size,
                              hipStream_t stream) {
  const float* x    = (const float*)d_in[0];
  const float* adj  = (const float*)d_in[1];
  const float* W    = (const float*)d_in[2];
  const float* bias = (const float*)d_in[3];
  float* out = (float*)d_out;

  char* ws = (char*)d_ws;
  float* dis = (float*)ws;                   // 64 KB
  bf16* WT   = (bf16*)(ws + (64 << 10));     // 128 KB
  bf16* gT   = (bf16*)(ws + (192 << 10));    // 8 MB

  deg_wt_kernel<<<BB * NN / 4 + 64, 256, 0, stream>>>(adj, W, dis, WT);
  gemm1_kernel<<<256, 256, 0, stream>>>(x, WT, dis, gT);
  gemm2_kernel<<<512, 256, 0, stream>>>(adj, gT, dis, bias, out);
}

// Round 4
// 77.077 us; speedup vs baseline: 1.8690x; 1.8690x over previous
//
#include <hip/hip_runtime.h>
#include <hip/hip_bf16.h>

// GCNConvAdj: out = D^-1/2 (A+I) D^-1/2 (x W) + b
// B=8, N=2048, F_IN=F_OUT=256. f32 in/out; bf16 MFMA internals.
// R4: R2 pipeline (degconv->adjBF bf16; all-gload_lds gemm2) +
//     gemm2 at 2 blocks/CU (BM=64,BN=128, 48KB LDS) + coalesced degconv stores.
#define BB 8
#define NN 2048
#define FF 256
#define NT (NN / 64)   // 32 K-steps of BK=64

typedef __attribute__((ext_vector_type(8))) short short8;
typedef __attribute__((ext_vector_type(4))) short short4v;
typedef __attribute__((ext_vector_type(4))) float f32x4;
typedef __hip_bfloat16 bf16;

__device__ inline short f2bf(float x) {
  unsigned u = __builtin_bit_cast(unsigned, x);
  unsigned r = (u + 0x7fffu + ((u >> 16) & 1u)) >> 16;
  return (short)r;
}

__device__ inline void gl2lds16(const void* g, void* l) {
  __builtin_amdgcn_global_load_lds((const __attribute__((address_space(1))) void*)g,
                                   (__attribute__((address_space(3))) void*)l, 16, 0, 0);
}

// -- kernel 1: deg + convert (adjBF = bf16(dis_r*(adj+I))) + wt (WT bf16) ----
__global__ __launch_bounds__(256)
void degconv_wt_kernel(const float* __restrict__ adj, const float* __restrict__ W,
                       float* __restrict__ dis, bf16* __restrict__ WT,
                       bf16* __restrict__ adjBF) {
  if (blockIdx.x >= BB * NN / 4) {
    int t2 = (blockIdx.x - BB * NN / 4) * 256 + threadIdx.x;   // 0..16383
    int k = t2 >> 6, oc = (t2 & 63) * 4;
    float4 v = *reinterpret_cast<const float4*>(W + (size_t)k * FF + oc);
    *reinterpret_cast<short*>(WT + (size_t)(oc + 0) * FF + k) = f2bf(v.x);
    *reinterpret_cast<short*>(WT + (size_t)(oc + 1) * FF + k) = f2bf(v.y);
    *reinterpret_cast<short*>(WT + (size_t)(oc + 2) * FF + k) = f2bf(v.z);
    *reinterpret_cast<short*>(WT + (size_t)(oc + 3) * FF + k) = f2bf(v.w);
    return;
  }
  int wid = threadIdx.x >> 6, lane = threadIdx.x & 63;
  int row = blockIdx.x * 4 + wid;                       // 0 .. BB*NN-1
  const float4* a4 = reinterpret_cast<const float4*>(adj + (size_t)row * NN);
  float4 v[8];
  float s = 0.f;
#pragma unroll
  for (int i = 0; i < 4; i++) {
    v[2 * i]     = a4[i * 128 + 2 * lane];      // lane holds 8 contiguous f32
    v[2 * i + 1] = a4[i * 128 + 2 * lane + 1];  // per 512-col chunk
    s += v[2*i].x + v[2*i].y + v[2*i].z + v[2*i].w
       + v[2*i+1].x + v[2*i+1].y + v[2*i+1].z + v[2*i+1].w;
  }
#pragma unroll
  for (int off = 1; off < 64; off <<= 1) s += __shfl_xor(s, off, 64);
  float d = rsqrtf(s + 1.0f);
  if (lane == 0) dis[row] = d;
  // fold +I before scaling: v[i] covers cols (i>>1)*512 + 8*lane + 4*(i&1) ..+4
  int rb = row & (NN - 1);
#pragma unroll
  for (int i = 0; i < 8; i++) {
    int dd = rb - ((i >> 1) * 512 + 8 * lane + 4 * (i & 1));
    v[i].x += (dd == 0) ? 1.0f : 0.0f;
    v[i].y += (dd == 1) ? 1.0f : 0.0f;
    v[i].z += (dd == 2) ? 1.0f : 0.0f;
    v[i].w += (dd == 3) ? 1.0f : 0.0f;
  }
  bf16* orow = adjBF + (size_t)row * NN;
#pragma unroll
  for (int i = 0; i < 4; i++) {
    short8 w;
    w[0] = f2bf(v[2*i].x * d);   w[1] = f2bf(v[2*i].y * d);
    w[2] = f2bf(v[2*i].z * d);   w[3] = f2bf(v[2*i].w * d);
    w[4] = f2bf(v[2*i+1].x * d); w[5] = f2bf(v[2*i+1].y * d);
    w[6] = f2bf(v[2*i+1].z * d); w[7] = f2bf(v[2*i+1].w * d);
    *reinterpret_cast<short8*>(orow + i * 512 + 8 * lane) = w;   // 16B coalesced
  }
}

// ---------------- kernel 2: gT[b][o][m] = dis[m] * (x@W)[m][o] (bf16) -------
__global__ __launch_bounds__(256)
void gemm1_kernel(const float* __restrict__ x, const bf16* __restrict__ WT,
                  const float* __restrict__ dis, bf16* __restrict__ gT) {
  __shared__ bf16 lA[128][40];
  __shared__ bf16 lB[128][40];
  int bid = blockIdx.x;
  int mtile = bid & 127, otile = bid >> 7;   // o-tile twins share an XCD
  int m0 = mtile * 128, o0 = otile * 128;
  int t = threadIdx.x, wid = t >> 6, lane = t & 63;
  int wr = wid >> 1, wc = wid & 1;
  int srow = t >> 1, sseg = t & 1;
  const int r16 = lane & 15, kb = lane >> 4;

  f32x4 acc[4][4];
#pragma unroll
  for (int i = 0; i < 4; i++)
#pragma unroll
    for (int j = 0; j < 4; j++) acc[i][j] = (f32x4){0.f, 0.f, 0.f, 0.f};

  for (int k0 = 0; k0 < FF; k0 += 32) {
    {
      const float4* ap = reinterpret_cast<const float4*>(
          x + (size_t)(m0 + srow) * FF + k0 + sseg * 16);
      float arr[16];
      float4 v0 = ap[0], v1 = ap[1], v2 = ap[2], v3 = ap[3];
      arr[0]=v0.x; arr[1]=v0.y; arr[2]=v0.z; arr[3]=v0.w;
      arr[4]=v1.x; arr[5]=v1.y; arr[6]=v1.z; arr[7]=v1.w;
      arr[8]=v2.x; arr[9]=v2.y; arr[10]=v2.z; arr[11]=v2.w;
      arr[12]=v3.x; arr[13]=v3.y; arr[14]=v3.z; arr[15]=v3.w;
      short8 w0, w1;
#pragma unroll
      for (int e = 0; e < 8; e++) { w0[e] = f2bf(arr[e]); w1[e] = f2bf(arr[8 + e]); }
      *reinterpret_cast<short8*>(&lA[srow][sseg * 16]) = w0;
      *reinterpret_cast<short8*>(&lA[srow][sseg * 16 + 8]) = w1;
    }
    {
      const short8* bp = reinterpret_cast<const short8*>(
          WT + (size_t)(o0 + srow) * FF + k0 + sseg * 16);
      *reinterpret_cast<short8*>(&lB[srow][sseg * 16]) = bp[0];
      *reinterpret_cast<short8*>(&lB[srow][sseg * 16 + 8]) = bp[1];
    }
    __syncthreads();
    short8 af[4], bfr[4];
#pragma unroll
    for (int mf = 0; mf < 4; mf++)
      af[mf] = *reinterpret_cast<const short8*>(&lA[wr * 64 + mf * 16 + r16][kb * 8]);
#pragma unroll
    for (int nf = 0; nf < 4; nf++)
      bfr[nf] = *reinterpret_cast<const short8*>(&lB[wc * 64 + nf * 16 + r16][kb * 8]);
#pragma unroll
    for (int mf = 0; mf < 4; mf++)
#pragma unroll
      for (int nf = 0; nf < 4; nf++)
        acc[mf][nf] = __builtin_amdgcn_mfma_f32_16x16x32_bf16(af[mf], bfr[nf], acc[mf][nf], 0, 0, 0);
    __syncthreads();
  }

  int b = m0 >> 11;
#pragma unroll
  for (int mf = 0; mf < 4; mf++) {
    int mloc = wr * 64 + mf * 16 + (lane >> 4) * 4;
    int mg = m0 + mloc;
    float4 d4 = *reinterpret_cast<const float4*>(dis + mg);
#pragma unroll
    for (int nf = 0; nf < 4; nf++) {
      int o = o0 + wc * 64 + nf * 16 + r16;
      f32x4 v = acc[mf][nf];
      short4v w;
      w[0] = f2bf(v[0] * d4.x); w[1] = f2bf(v[1] * d4.y);
      w[2] = f2bf(v[2] * d4.z); w[3] = f2bf(v[3] * d4.w);
      *reinterpret_cast<short4v*>(gT + ((size_t)b * FF + o) * NN + (mg & (NN - 1))) = w;
    }
  }
}

// ------- kernel 3: out[b][n][o] = (adjBF @ gT^T)[n][o] + bias[o] ------------
// BM=64, BN=128, BK=64; 512 blocks = 2/CU (48KB LDS). All-gload_lds staging
// with both-sides slot swizzle; 2-buf stage-before-compute.
__global__ __launch_bounds__(256, 2)
void gemm2_kernel(const bf16* __restrict__ adjBF, const bf16* __restrict__ gT,
                  const float* __restrict__ bias, float* __restrict__ out) {
  __shared__ __align__(16) bf16 lA[2][64 * 64];    // 16 KB
  __shared__ __align__(16) bf16 lB[2][128 * 64];   // 32 KB
  int bid = blockIdx.x;
  int ob = bid >> 8, g = bid & 255;     // twins g,g+256 -> same XCD (bid%8 inv)
  int batch = g >> 5, mtile = g & 31;
  int n0 = mtile * 64, o0 = ob * 128;
  const bf16* Ab = adjBF + ((size_t)batch * NN + n0) * NN;
  const bf16* Bt = gT + ((size_t)batch * FF + o0) * NN;

  int t = threadIdx.x, wid = t >> 6, lane = t & 63;
  int wr = wid >> 1, wc = wid & 1;               // 2(M) x 2(N) waves, 32x64 each
  const int r16 = lane & 15, kb = lane >> 4;
  int trow = t >> 3, gslot = (t & 7) ^ (trow & 7);
  const bf16* Ag = Ab + (size_t)trow * NN + 8 * gslot;
  const bf16* Bg = Bt + (size_t)trow * NN + 8 * gslot;

  f32x4 acc[2][4];
#pragma unroll
  for (int i = 0; i < 2; i++)
#pragma unroll
    for (int j = 0; j < 4; j++) acc[i][j] = (f32x4){0.f, 0.f, 0.f, 0.f};

  auto stage = [&](int buf, int ks) {
    bf16* la = &lA[buf][wid * 512];
    bf16* lb = &lB[buf][wid * 512];
#pragma unroll
    for (int q = 0; q < 2; q++)
      gl2lds16(Ag + (size_t)q * 32 * NN + ks * 64, la + q * 2048);
#pragma unroll
    for (int q = 0; q < 4; q++)
      gl2lds16(Bg + (size_t)q * 32 * NN + ks * 64, lb + q * 2048);
  };

  stage(0, 0);
  __syncthreads();
  int cur = 0;
#pragma unroll 1
  for (int ks = 0; ks < NT; ++ks) {
    if (ks + 1 < NT) stage(cur ^ 1, ks + 1);
    const bf16* sa = lA[cur];
    const bf16* sb = lB[cur];
#pragma unroll
    for (int kk = 0; kk < 2; kk++) {
      short8 af[2], bfr[4];
#pragma unroll
      for (int mf = 0; mf < 2; mf++) {
        int ra = wr * 32 + mf * 16 + r16;
        int slot = ((kk << 2) | kb) ^ (ra & 7);
        af[mf] = *reinterpret_cast<const short8*>(&sa[ra * 64 + slot * 8]);
      }
#pragma unroll
      for (int nf = 0; nf < 4; nf++) {
        int rbr = wc * 64 + nf * 16 + r16;
        int slot = ((kk << 2) | kb) ^ (rbr & 7);
        bfr[nf] = *reinterpret_cast<const short8*>(&sb[rbr * 64 + slot * 8]);
      }
#pragma unroll
      for (int mf = 0; mf < 2; mf++)
#pragma unroll
        for (int nf = 0; nf < 4; nf++)
          acc[mf][nf] = __builtin_amdgcn_mfma_f32_16x16x32_bf16(af[mf], bfr[nf], acc[mf][nf], 0, 0, 0);
    }
    __syncthreads();
    cur ^= 1;
  }

  float bv[4];
#pragma unroll
  for (int nf = 0; nf < 4; nf++) bv[nf] = bias[o0 + wc * 64 + nf * 16 + r16];
#pragma unroll
  for (int mf = 0; mf < 2; mf++) {
    int ng = n0 + wr * 32 + mf * 16 + (lane >> 4) * 4;
    float* op0 = out + ((size_t)batch * NN + ng) * FF;
#pragma unroll
    for (int nf = 0; nf < 4; nf++) {
      int o = o0 + wc * 64 + nf * 16 + r16;
      f32x4 v = acc[mf][nf];
      op0[0 * FF + o] = v[0] + bv[nf];
      op0[1 * FF + o] = v[1] + bv[nf];
      op0[2 * FF + o] = v[2] + bv[nf];
      op0[3 * FF + o] = v[3] + bv[nf];
    }
  }
}

extern "C" void kernel_launch(void* const* d_in, const int* in_sizes, int n_in,
                              void* d_out, int out_size, void* d_ws, size_t ws_size,
                              hipStream_t stream) {
  const float* x    = (const float*)d_in[0];
  const float* adj  = (const float*)d_in[1];
  const float* W    = (const float*)d_in[2];
  const float* bias = (const float*)d_in[3];
  float* out = (float*)d_out;

  char* ws = (char*)d_ws;
  float* dis  = (float*)ws;                              // 64 KB
  bf16* WT    = (bf16*)(ws + (64 << 10));                // 128 KB
  bf16* gT    = (bf16*)(ws + (192 << 10));               // 8 MB
  bf16* adjBF = (bf16*)(ws + (192 << 10) + (8 << 20));   // 64 MB

  degconv_wt_kernel<<<BB * NN / 4 + 64, 256, 0, stream>>>(adj, W, dis, WT, adjBF);
  gemm1_kernel<<<256, 256, 0, stream>>>(x, WT, dis, gT);
  gemm2_kernel<<<512, 256, 0, stream>>>(adjBF, gT, bias, out);
}

// Round 5
// 76.334 us; speedup vs baseline: 1.8872x; 1.0097x over previous
//
#include <hip/hip_runtime.h>
#include <hip/hip_bf16.h>

// GCNConvAdj: out = D^-1/2 (A+I) D^-1/2 (x W) + b
// B=8, N=2048, F_IN=F_OUT=256. f32 in/out; bf16 MFMA internals.
// R5: gemm2 re-tiled BM=64,BN=64 -> 1024 blocks = 4 blocks/CU (m114 overlap),
//     T5 setprio around MFMA cluster. degconv/gemm1 unchanged from R4.
#define BB 8
#define NN 2048
#define FF 256
#define NT (NN / 64)   // 32 K-steps of BK=64

typedef __attribute__((ext_vector_type(8))) short short8;
typedef __attribute__((ext_vector_type(4))) short short4v;
typedef __attribute__((ext_vector_type(4))) float f32x4;
typedef __hip_bfloat16 bf16;

__device__ inline short f2bf(float x) {
  unsigned u = __builtin_bit_cast(unsigned, x);
  unsigned r = (u + 0x7fffu + ((u >> 16) & 1u)) >> 16;
  return (short)r;
}

__device__ inline void gl2lds16(const void* g, void* l) {
  __builtin_amdgcn_global_load_lds((const __attribute__((address_space(1))) void*)g,
                                   (__attribute__((address_space(3))) void*)l, 16, 0, 0);
}

// -- kernel 1: deg + convert (adjBF = bf16(dis_r*(adj+I))) + wt (WT bf16) ----
__global__ __launch_bounds__(256)
void degconv_wt_kernel(const float* __restrict__ adj, const float* __restrict__ W,
                       float* __restrict__ dis, bf16* __restrict__ WT,
                       bf16* __restrict__ adjBF) {
  if (blockIdx.x >= BB * NN / 4) {
    int t2 = (blockIdx.x - BB * NN / 4) * 256 + threadIdx.x;   // 0..16383
    int k = t2 >> 6, oc = (t2 & 63) * 4;
    float4 v = *reinterpret_cast<const float4*>(W + (size_t)k * FF + oc);
    *reinterpret_cast<short*>(WT + (size_t)(oc + 0) * FF + k) = f2bf(v.x);
    *reinterpret_cast<short*>(WT + (size_t)(oc + 1) * FF + k) = f2bf(v.y);
    *reinterpret_cast<short*>(WT + (size_t)(oc + 2) * FF + k) = f2bf(v.z);
    *reinterpret_cast<short*>(WT + (size_t)(oc + 3) * FF + k) = f2bf(v.w);
    return;
  }
  int wid = threadIdx.x >> 6, lane = threadIdx.x & 63;
  int row = blockIdx.x * 4 + wid;                       // 0 .. BB*NN-1
  const float4* a4 = reinterpret_cast<const float4*>(adj + (size_t)row * NN);
  float4 v[8];
  float s = 0.f;
#pragma unroll
  for (int i = 0; i < 4; i++) {
    v[2 * i]     = a4[i * 128 + 2 * lane];
    v[2 * i + 1] = a4[i * 128 + 2 * lane + 1];
    s += v[2*i].x + v[2*i].y + v[2*i].z + v[2*i].w
       + v[2*i+1].x + v[2*i+1].y + v[2*i+1].z + v[2*i+1].w;
  }
#pragma unroll
  for (int off = 1; off < 64; off <<= 1) s += __shfl_xor(s, off, 64);
  float d = rsqrtf(s + 1.0f);
  if (lane == 0) dis[row] = d;
  int rb = row & (NN - 1);
#pragma unroll
  for (int i = 0; i < 8; i++) {
    int dd = rb - ((i >> 1) * 512 + 8 * lane + 4 * (i & 1));
    v[i].x += (dd == 0) ? 1.0f : 0.0f;
    v[i].y += (dd == 1) ? 1.0f : 0.0f;
    v[i].z += (dd == 2) ? 1.0f : 0.0f;
    v[i].w += (dd == 3) ? 1.0f : 0.0f;
  }
  bf16* orow = adjBF + (size_t)row * NN;
#pragma unroll
  for (int i = 0; i < 4; i++) {
    short8 w;
    w[0] = f2bf(v[2*i].x * d);   w[1] = f2bf(v[2*i].y * d);
    w[2] = f2bf(v[2*i].z * d);   w[3] = f2bf(v[2*i].w * d);
    w[4] = f2bf(v[2*i+1].x * d); w[5] = f2bf(v[2*i+1].y * d);
    w[6] = f2bf(v[2*i+1].z * d); w[7] = f2bf(v[2*i+1].w * d);
    *reinterpret_cast<short8*>(orow + i * 512 + 8 * lane) = w;
  }
}

// ---------------- kernel 2: gT[b][o][m] = dis[m] * (x@W)[m][o] (bf16) -------
__global__ __launch_bounds__(256)
void gemm1_kernel(const float* __restrict__ x, const bf16* __restrict__ WT,
                  const float* __restrict__ dis, bf16* __restrict__ gT) {
  __shared__ bf16 lA[128][40];
  __shared__ bf16 lB[128][40];
  int bid = blockIdx.x;
  int mtile = bid & 127, otile = bid >> 7;
  int m0 = mtile * 128, o0 = otile * 128;
  int t = threadIdx.x, wid = t >> 6, lane = t & 63;
  int wr = wid >> 1, wc = wid & 1;
  int srow = t >> 1, sseg = t & 1;
  const int r16 = lane & 15, kb = lane >> 4;

  f32x4 acc[4][4];
#pragma unroll
  for (int i = 0; i < 4; i++)
#pragma unroll
    for (int j = 0; j < 4; j++) acc[i][j] = (f32x4){0.f, 0.f, 0.f, 0.f};

  for (int k0 = 0; k0 < FF; k0 += 32) {
    {
      const float4* ap = reinterpret_cast<const float4*>(
          x + (size_t)(m0 + srow) * FF + k0 + sseg * 16);
      float arr[16];
      float4 v0 = ap[0], v1 = ap[1], v2 = ap[2], v3 = ap[3];
      arr[0]=v0.x; arr[1]=v0.y; arr[2]=v0.z; arr[3]=v0.w;
      arr[4]=v1.x; arr[5]=v1.y; arr[6]=v1.z; arr[7]=v1.w;
      arr[8]=v2.x; arr[9]=v2.y; arr[10]=v2.z; arr[11]=v2.w;
      arr[12]=v3.x; arr[13]=v3.y; arr[14]=v3.z; arr[15]=v3.w;
      short8 w0, w1;
#pragma unroll
      for (int e = 0; e < 8; e++) { w0[e] = f2bf(arr[e]); w1[e] = f2bf(arr[8 + e]); }
      *reinterpret_cast<short8*>(&lA[srow][sseg * 16]) = w0;
      *reinterpret_cast<short8*>(&lA[srow][sseg * 16 + 8]) = w1;
    }
    {
      const short8* bp = reinterpret_cast<const short8*>(
          WT + (size_t)(o0 + srow) * FF + k0 + sseg * 16);
      *reinterpret_cast<short8*>(&lB[srow][sseg * 16]) = bp[0];
      *reinterpret_cast<short8*>(&lB[srow][sseg * 16 + 8]) = bp[1];
    }
    __syncthreads();
    short8 af[4], bfr[4];
#pragma unroll
    for (int mf = 0; mf < 4; mf++)
      af[mf] = *reinterpret_cast<const short8*>(&lA[wr * 64 + mf * 16 + r16][kb * 8]);
#pragma unroll
    for (int nf = 0; nf < 4; nf++)
      bfr[nf] = *reinterpret_cast<const short8*>(&lB[wc * 64 + nf * 16 + r16][kb * 8]);
#pragma unroll
    for (int mf = 0; mf < 4; mf++)
#pragma unroll
      for (int nf = 0; nf < 4; nf++)
        acc[mf][nf] = __builtin_amdgcn_mfma_f32_16x16x32_bf16(af[mf], bfr[nf], acc[mf][nf], 0, 0, 0);
    __syncthreads();
  }

  int b = m0 >> 11;
#pragma unroll
  for (int mf = 0; mf < 4; mf++) {
    int mloc = wr * 64 + mf * 16 + (lane >> 4) * 4;
    int mg = m0 + mloc;
    float4 d4 = *reinterpret_cast<const float4*>(dis + mg);
#pragma unroll
    for (int nf = 0; nf < 4; nf++) {
      int o = o0 + wc * 64 + nf * 16 + r16;
      f32x4 v = acc[mf][nf];
      short4v w;
      w[0] = f2bf(v[0] * d4.x); w[1] = f2bf(v[1] * d4.y);
      w[2] = f2bf(v[2] * d4.z); w[3] = f2bf(v[3] * d4.w);
      *reinterpret_cast<short4v*>(gT + ((size_t)b * FF + o) * NN + (mg & (NN - 1))) = w;
    }
  }
}

// ------- kernel 3: out[b][n][o] = (adjBF @ gT^T)[n][o] + bias[o] ------------
// BM=64, BN=64, BK=64; 1024 blocks = 4/CU (32KB LDS). All-gload_lds staging,
// both-sides slot swizzle, stage-before-compute, setprio on MFMA cluster.
__global__ __launch_bounds__(256, 4)
void gemm2_kernel(const bf16* __restrict__ adjBF, const bf16* __restrict__ gT,
                  const float* __restrict__ bias, float* __restrict__ out) {
  __shared__ __align__(16) bf16 lA[2][64 * 64];    // 8 KB each buf
  __shared__ __align__(16) bf16 lB[2][64 * 64];
  int bid = blockIdx.x;
  // decode keeping bid%8 invariant across the 4 o-tiles of one (batch,mtile)
  int x3 = bid & 7, idx = bid >> 3;      // idx in [0,128)
  int ob = idx & 3, hi = idx >> 2;       // hi in [0,32)
  int gg = hi * 8 + x3;                  // [0,256)
  int batch = gg >> 5, mtile = gg & 31;
  int n0 = mtile * 64, o0 = ob * 64;
  const bf16* Ab = adjBF + ((size_t)batch * NN + n0) * NN;
  const bf16* Bt = gT + ((size_t)batch * FF + o0) * NN;

  int t = threadIdx.x, wid = t >> 6, lane = t & 63;
  int wr = wid >> 1, wc = wid & 1;               // 2x2 waves, 32x32 each
  const int r16 = lane & 15, kb = lane >> 4;
  int trow = t >> 3, tslot = t & 7;              // 32 rows, 8 slots/row

  f32x4 acc[2][2];
#pragma unroll
  for (int i = 0; i < 2; i++)
#pragma unroll
    for (int j = 0; j < 2; j++) acc[i][j] = (f32x4){0.f, 0.f, 0.f, 0.f};

  auto stage = [&](int buf, int ks) {
    bf16* la = &lA[buf][wid * 512];
    bf16* lb = &lB[buf][wid * 512];
#pragma unroll
    for (int q = 0; q < 2; q++) {
      int r = q * 32 + trow;
      int gs = tslot ^ (r & 7);
      gl2lds16(Ab + (size_t)r * NN + ks * 64 + 8 * gs, la + q * 2048);
      gl2lds16(Bt + (size_t)r * NN + ks * 64 + 8 * gs, lb + q * 2048);
    }
  };

  stage(0, 0);
  __syncthreads();
  int cur = 0;
#pragma unroll 1
  for (int ks = 0; ks < NT; ++ks) {
    if (ks + 1 < NT) stage(cur ^ 1, ks + 1);
    const bf16* sa = lA[cur];
    const bf16* sb = lB[cur];
    short8 af[2][2], bfr[2][2];
#pragma unroll
    for (int kk = 0; kk < 2; kk++) {
#pragma unroll
      for (int mf = 0; mf < 2; mf++) {
        int ra = wr * 32 + mf * 16 + r16;
        int slot = ((kk << 2) | kb) ^ (ra & 7);
        af[kk][mf] = *reinterpret_cast<const short8*>(&sa[ra * 64 + slot * 8]);
      }
#pragma unroll
      for (int nf = 0; nf < 2; nf++) {
        int rbr = wc * 32 + nf * 16 + r16;
        int slot = ((kk << 2) | kb) ^ (rbr & 7);
        bfr[kk][nf] = *reinterpret_cast<const short8*>(&sb[rbr * 64 + slot * 8]);
      }
    }
    __builtin_amdgcn_s_setprio(1);
#pragma unroll
    for (int kk = 0; kk < 2; kk++)
#pragma unroll
      for (int mf = 0; mf < 2; mf++)
#pragma unroll
        for (int nf = 0; nf < 2; nf++)
          acc[mf][nf] = __builtin_amdgcn_mfma_f32_16x16x32_bf16(
              af[kk][mf], bfr[kk][nf], acc[mf][nf], 0, 0, 0);
    __builtin_amdgcn_s_setprio(0);
    __syncthreads();
    cur ^= 1;
  }

  float bv[2];
#pragma unroll
  for (int nf = 0; nf < 2; nf++) bv[nf] = bias[o0 + wc * 32 + nf * 16 + r16];
#pragma unroll
  for (int mf = 0; mf < 2; mf++) {
    int ng = n0 + wr * 32 + mf * 16 + (lane >> 4) * 4;
    float* op0 = out + ((size_t)batch * NN + ng) * FF;
#pragma unroll
    for (int nf = 0; nf < 2; nf++) {
      int o = o0 + wc * 32 + nf * 16 + r16;
      f32x4 v = acc[mf][nf];
      op0[0 * FF + o] = v[0] + bv[nf];
      op0[1 * FF + o] = v[1] + bv[nf];
      op0[2 * FF + o] = v[2] + bv[nf];
      op0[3 * FF + o] = v[3] + bv[nf];
    }
  }
}

extern "C" void kernel_launch(void* const* d_in, const int* in_sizes, int n_in,
                              void* d_out, int out_size, void* d_ws, size_t ws_size,
                              hipStream_t stream) {
  const float* x    = (const float*)d_in[0];
  const float* adj  = (const float*)d_in[1];
  const float* W    = (const float*)d_in[2];
  const float* bias = (const float*)d_in[3];
  float* out = (float*)d_out;

  char* ws = (char*)d_ws;
  float* dis  = (float*)ws;                              // 64 KB
  bf16* WT    = (bf16*)(ws + (64 << 10));                // 128 KB
  bf16* gT    = (bf16*)(ws + (192 << 10));               // 8 MB
  bf16* adjBF = (bf16*)(ws + (192 << 10) + (8 << 20));   // 64 MB

  degconv_wt_kernel<<<BB * NN / 4 + 64, 256, 0, stream>>>(adj, W, dis, WT, adjBF);
  gemm1_kernel<<<256, 256, 0, stream>>>(x, WT, dis, gT);
  gemm2_kernel<<<1024, 256, 0, stream>>>(adjBF, gT, bias, out);
}